// Round 4
// baseline (253.730 us; speedup 1.0000x reference)
//
#include <hip/hip_runtime.h>
#include <cstdint>
#include <cstddef>

typedef __bf16 bf16x8 __attribute__((ext_vector_type(8)));
typedef float f32x4 __attribute__((ext_vector_type(4)));
typedef float f32x16 __attribute__((ext_vector_type(16)));
typedef unsigned int u32x2v __attribute__((ext_vector_type(2)));
typedef unsigned short u16;

constexpr int S_LEN  = 2048;
constexpr int DMODEL = 2048;
constexpr int NHEAD  = 16;
constexpr int HDIM   = 128;
constexpr int WIN    = 512;

#define AS1 __attribute__((address_space(1)))
#define AS3 __attribute__((address_space(3)))
#define CFENCE asm volatile("" ::: "memory")
#define BAR() do { CFENCE; __builtin_amdgcn_s_barrier(); CFENCE; } while (0)
#define WAITVM(n) asm volatile("s_waitcnt vmcnt(" #n ")" ::: "memory")

__device__ __forceinline__ u16 f2bf(float f) {
  union { float ff; uint32_t u; } a; a.ff = f;
  return (u16)((a.u + 0x7fffu + ((a.u >> 16) & 1u)) >> 16);  // RNE
}

__device__ __forceinline__ uint32_t cvtpk(float lo, float hi) {
  uint32_t r;
  asm("v_cvt_pk_bf16_f32 %0, %1, %2" : "=v"(r) : "v"(lo), "v"(hi));
  return r;
}

// ---------------- fused fp32 -> bf16 convert (x, Wq, Wk, Wv, Wo) ----------------
__global__ void cvt_all(const float* __restrict__ x,  const float* __restrict__ wq,
                        const float* __restrict__ wk, const float* __restrict__ wv,
                        const float* __restrict__ wo,
                        u16* __restrict__ xb,  u16* __restrict__ wqb,
                        u16* __restrict__ wkb, u16* __restrict__ wvb,
                        u16* __restrict__ wob) {
  const int total = 6291456;  // float4 count: x 2M, each W 1M
  int i = blockIdx.x * blockDim.x + threadIdx.x;
  const int stride = gridDim.x * blockDim.x;
  for (; i < total; i += stride) {
    const int r = i >> 20;
    const float* src; u16* dst; int off;
    if (r < 2)       { src = x;  dst = xb;  off = i; }
    else if (r == 2) { src = wq; dst = wqb; off = i - (2 << 20); }
    else if (r == 3) { src = wk; dst = wkb; off = i - (3 << 20); }
    else if (r == 4) { src = wv; dst = wvb; off = i - (4 << 20); }
    else             { src = wo; dst = wob; off = i - (5 << 20); }
    float4 v = reinterpret_cast<const float4*>(src)[off];
    uint2 pk;
    pk.x = (uint32_t)f2bf(v.x) | ((uint32_t)f2bf(v.y) << 16);
    pk.y = (uint32_t)f2bf(v.z) | ((uint32_t)f2bf(v.w) << 16);
    reinterpret_cast<uint2*>(dst)[off] = pk;
  }
}

// ---------------- rope tables (fp64 for accuracy, tiny) ----------------
__global__ void rope_kernel(float* __restrict__ rc, float* __restrict__ rs) {
  const int i = blockIdx.x * blockDim.x + threadIdx.x;  // s*64 + f
  const int s = i >> 6, f = i & 63;
  const double inv = exp(-(double)f * (log(10000.0) / 64.0));
  const double a = (double)s * inv;
  rc[i] = (float)cos(a);
  rs[i] = (float)sin(a);
}

// ---------------- 256-row-tile GEMM, 8-phase counted-vmcnt pipeline ----------------
// MODE 0: fused QKV (BN=256, grid 384, regions by ct>>3, rope/transpose epilogues)
// MODE 1: O projection (BN=128, grid 256, fp32 epilogue)
// LDS: ring of 4 subtile slots per matrix (K=32 each), fragment-order layout ->
// linear conflict-free ds_read_b128; global source pre-permuted (rule #21).
template<int MODE>
__global__ __launch_bounds__(512, 2)
void gemm256(const u16* __restrict__ A,
             const u16* __restrict__ B0, const u16* __restrict__ B1,
             const u16* __restrict__ B2,
             u16* __restrict__ qout, u16* __restrict__ kout, u16* __restrict__ vtout,
             float* __restrict__ oout,
             const float* __restrict__ rc, const float* __restrict__ rs) {
  constexpr int K = DMODEL;
  constexpr int NK = K / 32;                 // 64 subtiles
  constexpr int NF = (MODE == 0) ? 4 : 2;    // B n-frags per wave (BN = 64*NF... per-wave 16*NF cols)
  constexpr int BSLOT = (MODE == 0) ? 8192 : 4096;   // u16 per B subtile slot
  constexpr int NBL = (MODE == 0) ? 2 : 1;   // B stage loads per thread
  __shared__ __align__(16) u16 sm[(MODE == 0) ? 65536 : 49152];

  const int lin = blockIdx.x;
  const int xcd = lin & 7, idx = lin >> 3;
  int mt, ct;
  if constexpr (MODE == 0) { mt = idx & 15; ct = xcd * 3 + (idx >> 4); }   // 24 ct
  else                     { mt = idx & 15; ct = xcd * 2 + (idx >> 4); }   // 16 ct
  const int region = (MODE == 0) ? (ct >> 3) : 0;
  const u16* Bw = (MODE == 0) ? (region == 0 ? B0 : region == 1 ? B1 : B2) : B0;
  const int brow = mt * 256;
  const int bcoll = (MODE == 0) ? (ct & 7) * 256 : ct * 128;

  const int tid = threadIdx.x;
  const int w = tid >> 6, lane = tid & 63;
  const int lr = lane & 15, lk = lane >> 4;
  const int wm = w >> 2, wn = w & 3;

  const u16* Ag = A  + (size_t)brow * K;
  const u16* Bg = Bw + (size_t)bcoll * K;
  u16* Asl = sm;
  u16* Bsl = sm + 32768;

  f32x4 acc[8][NF] = {};

  // stage one K=32 subtile, fragment-order dest (linear), per-lane permuted source
  auto stageA = [&](int s) {
    u16* slot = Asl + (s & 3) * 8192;
#pragma unroll
    for (int i = 0; i < 2; ++i) {
      const int MF = i * 8 + w;
      const u16* src = Ag + (size_t)(MF * 16 + lr) * K + s * 32 + lk * 8;
      __builtin_amdgcn_global_load_lds((const AS1 void*)src,
          (AS3 void*)(slot + (i * 512 + w * 64) * 8), 16, 0, 0);
    }
  };
  auto stageB = [&](int s) {
    u16* slot = Bsl + (s & 3) * BSLOT;
#pragma unroll
    for (int i = 0; i < NBL; ++i) {
      const int MF = i * 8 + w;
      const u16* src = Bg + (size_t)(MF * 16 + lr) * K + s * 32 + lk * 8;
      __builtin_amdgcn_global_load_lds((const AS1 void*)src,
          (AS3 void*)(slot + (i * 512 + w * 64) * 8), 16, 0, 0);
    }
  };

  // prologue: subtiles 0,1,2 in flight; wait subtile 0 resident
#pragma unroll
  for (int s = 0; s < 3; ++s) { stageA(s); stageB(s); }
  if constexpr (MODE == 0) WAITVM(8); else WAITVM(6);
  BAR();

  for (int s = 0; s < NK; ++s) {
    const u16* As = Asl + (s & 3) * 8192;
    const u16* Bs = Bsl + (s & 3) * BSLOT;
    // ---- phase 0: mf 0..3 ----
    bf16x8 afr[4], bfr[NF];
#pragma unroll
    for (int ml = 0; ml < 4; ++ml)
      afr[ml] = *reinterpret_cast<const bf16x8*>(As + ((wm * 8 + ml) * 64 + lk * 16 + lr) * 8);
#pragma unroll
    for (int nf = 0; nf < NF; ++nf)
      bfr[nf] = *reinterpret_cast<const bf16x8*>(Bs + ((wn * NF + nf) * 64 + lk * 16 + lr) * 8);
    if (s + 3 < NK) stageA(s + 3);
    BAR();
    __builtin_amdgcn_s_setprio(1);
#pragma unroll
    for (int ml = 0; ml < 4; ++ml)
#pragma unroll
      for (int nf = 0; nf < NF; ++nf)
        acc[ml][nf] = __builtin_amdgcn_mfma_f32_16x16x32_bf16(afr[ml], bfr[nf], acc[ml][nf], 0, 0, 0);
    __builtin_amdgcn_s_setprio(0);
    BAR();
    // ---- phase 1: mf 4..7 ----
    bf16x8 afr2[4];
#pragma unroll
    for (int ml = 0; ml < 4; ++ml)
      afr2[ml] = *reinterpret_cast<const bf16x8*>(As + ((wm * 8 + 4 + ml) * 64 + lk * 16 + lr) * 8);
    if (s + 3 < NK) stageB(s + 3);
    BAR();
    __builtin_amdgcn_s_setprio(1);
#pragma unroll
    for (int ml = 0; ml < 4; ++ml)
#pragma unroll
      for (int nf = 0; nf < NF; ++nf)
        acc[4 + ml][nf] = __builtin_amdgcn_mfma_f32_16x16x32_bf16(afr2[ml], bfr[nf], acc[4 + ml][nf], 0, 0, 0);
    __builtin_amdgcn_s_setprio(0);
    // counted wait: retire subtile s+1 (all of it) before next iteration reads it
    if constexpr (MODE == 0) {
      if (s < NK - 3) { WAITVM(8); } else if (s == NK - 3) { WAITVM(4); } else if (s == NK - 2) { WAITVM(0); }
    } else {
      if (s < NK - 3) { WAITVM(6); } else if (s == NK - 3) { WAITVM(3); } else if (s == NK - 2) { WAITVM(0); }
    }
    BAR();
  }

  // ---- epilogue ----  C frag: col = lane&15, row = lk*4 + j (m89)
  if constexpr (MODE == 1) {
#pragma unroll
    for (int mf = 0; mf < 8; ++mf) {
      const int gm0 = brow + wm * 128 + mf * 16 + lk * 4;
#pragma unroll
      for (int nf = 0; nf < NF; ++nf) {
        const int gn = bcoll + wn * (16 * NF) + nf * 16 + lr;
#pragma unroll
        for (int j = 0; j < 4; ++j)
          oout[(size_t)(gm0 + j) * DMODEL + gn] = acc[mf][nf][j];
      }
    }
  } else if (region == 2) {     // V: transposed [B,H,Dh,S] bf16
#pragma unroll
    for (int mf = 0; mf < 8; ++mf) {
      const int gm0 = brow + wm * 128 + mf * 16 + lk * 4;
      const int b = gm0 >> 11, s0 = gm0 & 2047;
#pragma unroll
      for (int nf = 0; nf < NF; ++nf) {
        const int gn = bcoll + wn * 64 + nf * 16 + lr;
        const int h = gn >> 7, dh = gn & 127;
        uint2 pk;
        pk.x = (uint32_t)f2bf(acc[mf][nf][0]) | ((uint32_t)f2bf(acc[mf][nf][1]) << 16);
        pk.y = (uint32_t)f2bf(acc[mf][nf][2]) | ((uint32_t)f2bf(acc[mf][nf][3]) << 16);
        *reinterpret_cast<uint2*>(&vtout[((size_t)((b * NHEAD + h) * HDIM + dh)) * S_LEN + s0]) = pk;
      }
    }
  } else {                      // Q/K: rope (+scale for Q), [B,H,S,Dh] bf16
    u16* QK = region == 0 ? qout : kout;
#pragma unroll
    for (int mf = 0; mf < 8; ++mf) {
      const int gm0 = brow + wm * 128 + mf * 16 + lk * 4;
      const int b = gm0 >> 11, s0 = gm0 & 2047;
#pragma unroll
      for (int nf = 0; nf < NF; ++nf) {
        const int gn = bcoll + wn * 64 + nf * 16 + lr;
        const int h = gn >> 7, dh = gn & 127;
        const int fi = dh >> 1;
        const bool ev = (dh & 1) == 0;
#pragma unroll
        for (int j = 0; j < 4; ++j) {
          float v = acc[mf][nf][j];
          float pp = __shfl_xor(v, 1, 64);        // partner channel (dh^1)
          const float c  = rc[(s0 + j) * 64 + fi];
          const float sn = rs[(s0 + j) * 64 + fi];
          float oo = ev ? (v * c - pp * sn) : (pp * sn + v * c);
          if (region == 0) oo *= 0.08838834764831845f;   // Dh^-0.5
          QK[((size_t)(b * NHEAD + h) * S_LEN + (s0 + j)) * HDIM + dh] = f2bf(oo);
        }
      }
    }
  }
}

// ---------------- sliding-window flash attention, LDS-staged K/V ----------------
__global__ __launch_bounds__(256, 2)
void swa3_kernel(const u16* __restrict__ Qp, const u16* __restrict__ Kp,
                 const u16* __restrict__ Vt, u16* __restrict__ AO) {
  __shared__ __align__(16) u16 Ksh[2][64 * 128];
  __shared__ __align__(16) u16 Vsh[2][128 * 64];

  const int lin = blockIdx.x + gridDim.x * blockIdx.y;   // 0..511
  const int slot = lin >> 3;
  const int bh = (lin & 7) * 4 + (slot >> 4);
  const int qt = slot & 15;

  const int w = threadIdx.x >> 6;
  const int lane = threadIdx.x & 63;
  const int lq = lane & 31, hi = lane >> 5;
  const int qb_blk = qt * 128;
  const int qw = qb_blk + w * 32;
  const int qq = qw + lq;

  const u16* Qb = Qp + (size_t)bh * S_LEN * HDIM;
  const u16* Kb = Kp + (size_t)bh * S_LEN * HDIM;
  const u16* Vb = Vt + (size_t)bh * HDIM * S_LEN;

  bf16x8 qf[8];
#pragma unroll
  for (int s = 0; s < 8; ++s)
    qf[s] = *reinterpret_cast<const bf16x8*>(&Qb[(size_t)qq * HDIM + s * 16 + hi * 8]);

  f32x16 ot[4] = {};
  float m = 0.f, lsum = 0.f;

  const int c_lo = (qb_blk >= WIN) ? qb_blk - WIN : 0;
  const int c_hi = qb_blk + 128;

  auto stage = [&](int buf, int kc) {
#pragma unroll
    for (int i = 0; i < 4; ++i) {       // K: 16 units/row
      const int u = i * 256 + w * 64 + lane;
      const int row = u >> 4, sl = (u & 15) ^ (row & 7);
      __builtin_amdgcn_global_load_lds(
          (const AS1 void*)(Kb + (size_t)(kc + row) * HDIM + sl * 8),
          (AS3 void*)(&Ksh[buf][(size_t)(i * 256 + w * 64) * 8]), 16, 0, 0);
    }
#pragma unroll
    for (int i = 0; i < 4; ++i) {       // V: 8 units/row
      const int u = i * 256 + w * 64 + lane;
      const int row = u >> 3, sl = (u & 7) ^ (row & 7);
      __builtin_amdgcn_global_load_lds(
          (const AS1 void*)(Vb + (size_t)row * S_LEN + kc + sl * 8),
          (AS3 void*)(&Vsh[buf][(size_t)(i * 256 + w * 64) * 8]), 16, 0, 0);
    }
  };

  int buf = 0;
  stage(0, c_lo);
  __syncthreads();

  for (int kc = c_lo; kc < c_hi; kc += 64, buf ^= 1) {
    if (kc + 64 < c_hi) stage(buf ^ 1, kc + 64);

#pragma unroll
    for (int half = 0; half < 2; ++half) {
      const int kch = kc + half * 32;
      if (kch > qw + 31 || kch < qw - 542) continue;

      f32x16 P = {};
#pragma unroll
      for (int s = 0; s < 8; ++s) {
        const int row = half * 32 + lq;
        const int byte = row * 256 + ((s * 32 + hi * 16) ^ ((row & 7) << 4));
        bf16x8 kf = *reinterpret_cast<const bf16x8*>(&Ksh[buf][byte >> 1]);
        P = __builtin_amdgcn_mfma_f32_32x32x16_bf16(kf, qf[s], P, 0, 0, 0);
      }

      const bool needmask = (kch + 32 > qw) || (qw + 31 - kch >= WIN);
      float p[16];
      float pmax = -1e30f;
#pragma unroll
      for (int r = 0; r < 16; ++r) {
        float v = P[r];
        if (needmask) {
          const int kk = kch + (r & 3) + ((r >> 2) << 3) + hi * 4;
          const bool keep = (qq >= kk) && (qq - kk < WIN);
          v = keep ? v : -1e30f;
        }
        p[r] = v;
        pmax = fmaxf(pmax, v);
      }

      if (__any(pmax - m > 8.f)) {
        const float rm = fmaxf(pmax, __shfl_xor(pmax, 32, 64));
        const float mnew = fmaxf(m, rm);
        const float alpha = __expf(m - mnew);
        lsum *= alpha;
#pragma unroll
        for (int dt = 0; dt < 4; ++dt)
#pragma unroll
          for (int r = 0; r < 16; ++r) ot[dt][r] *= alpha;
        m = mnew;
      }

      float ls = 0.f;
#pragma unroll
      for (int r = 0; r < 16; ++r) {
        p[r] = __expf(p[r] - m);
        ls += p[r];
      }
      lsum += ls;

      uint32_t W[8];
#pragma unroll
      for (int i = 0; i < 8; ++i) W[i] = cvtpk(p[2 * i], p[2 * i + 1]);
      u32x2v r02 = __builtin_amdgcn_permlane32_swap(W[0], W[2], false, false);
      u32x2v r13 = __builtin_amdgcn_permlane32_swap(W[1], W[3], false, false);
      u32x2v r46 = __builtin_amdgcn_permlane32_swap(W[4], W[6], false, false);
      u32x2v r57 = __builtin_amdgcn_permlane32_swap(W[5], W[7], false, false);

#pragma unroll
      for (int ks = 0; ks < 2; ++ks) {
        union { uint32_t u[4]; bf16x8 v; } pb;
        if (ks == 0) { pb.u[0] = r02[0]; pb.u[1] = r13[0]; pb.u[2] = r02[1]; pb.u[3] = r13[1]; }
        else         { pb.u[0] = r46[0]; pb.u[1] = r57[0]; pb.u[2] = r46[1]; pb.u[3] = r57[1]; }
#pragma unroll
        for (int dt = 0; dt < 4; ++dt) {
          const int d = dt * 32 + lq;
          const int byte = d * 128 + ((half * 64 + ks * 32 + hi * 16) ^ ((d & 7) << 4));
          bf16x8 vf = *reinterpret_cast<const bf16x8*>(&Vsh[buf][byte >> 1]);
          ot[dt] = __builtin_amdgcn_mfma_f32_32x32x16_bf16(vf, pb.v, ot[dt], 0, 0, 0);
        }
      }
    }
    __syncthreads();
  }

  const float lf = lsum + __shfl_xor(lsum, 32, 64);
  const float inv = 1.f / lf;
  const int b = bh >> 4, h = bh & 15;
  u16* Ob = AO + (size_t)(b * S_LEN + qq) * DMODEL + h * HDIM;
#pragma unroll
  for (int dt = 0; dt < 4; ++dt)
#pragma unroll
    for (int rq = 0; rq < 4; ++rq) {
      uint2 pk;
      pk.x = cvtpk(ot[dt][rq * 4 + 0] * inv, ot[dt][rq * 4 + 1] * inv);
      pk.y = cvtpk(ot[dt][rq * 4 + 2] * inv, ot[dt][rq * 4 + 3] * inv);
      *reinterpret_cast<uint2*>(&Ob[dt * 32 + rq * 8 + hi * 4]) = pk;
    }
}

extern "C" void kernel_launch(void* const* d_in, const int* in_sizes, int n_in,
                              void* d_out, int out_size, void* d_ws, size_t ws_size,
                              hipStream_t stream) {
  const float* x  = (const float*)d_in[0];
  const float* Wq = (const float*)d_in[1];
  const float* Wk = (const float*)d_in[2];
  const float* Wv = (const float*)d_in[3];
  const float* Wo = (const float*)d_in[4];
  float* out = (float*)d_out;

  u16* p = (u16*)d_ws;
  u16* xb  = p; p += (size_t)4096 * 2048;
  u16* wqb = p; p += (size_t)2048 * 2048;
  u16* wkb = p; p += (size_t)2048 * 2048;
  u16* wvb = p; p += (size_t)2048 * 2048;
  u16* wob = p; p += (size_t)2048 * 2048;
  u16* qb  = p; p += (size_t)32 * 2048 * 128;   // [B,H,S,Dh]
  u16* kb  = p; p += (size_t)32 * 2048 * 128;   // [B,H,S,Dh]
  u16* vtb = p; p += (size_t)32 * 128 * 2048;   // [B,H,Dh,S]
  u16* aob = p; p += (size_t)4096 * 2048;       // [B*S, D]
  float* rc = (float*)p;
  float* rs = rc + (size_t)2048 * 64;

  cvt_all<<<3072, 256, 0, stream>>>(x, Wq, Wk, Wv, Wo, xb, wqb, wkb, wvb, wob);
  rope_kernel<<<512, 256, 0, stream>>>(rc, rs);
  gemm256<0><<<384, 512, 0, stream>>>(xb, wqb, wkb, wvb, qb, kb, vtb, nullptr, rc, rs);
  swa3_kernel<<<dim3(16, 32), 256, 0, stream>>>(qb, kb, vtb, aob);
  gemm256<1><<<256, 512, 0, stream>>>(aob, wob, nullptr, nullptr, nullptr, nullptr, nullptr, out, nullptr, nullptr);
}

// Round 5
// 246.671 us; speedup vs baseline: 1.0286x; 1.0286x over previous
//
#include <hip/hip_runtime.h>
#include <cstdint>
#include <cstddef>

typedef __bf16 bf16x8 __attribute__((ext_vector_type(8)));
typedef float f32x4 __attribute__((ext_vector_type(4)));
typedef float f32x16 __attribute__((ext_vector_type(16)));
typedef unsigned int u32x2v __attribute__((ext_vector_type(2)));
typedef unsigned short u16;

constexpr int S_LEN  = 2048;
constexpr int DMODEL = 2048;
constexpr int NHEAD  = 16;
constexpr int HDIM   = 128;
constexpr int WIN    = 512;

#define AS1 __attribute__((address_space(1)))
#define AS3 __attribute__((address_space(3)))
#define BAR() do { asm volatile("" ::: "memory"); __builtin_amdgcn_s_barrier(); asm volatile("" ::: "memory"); } while (0)
#define WAITVM(n) asm volatile("s_waitcnt vmcnt(" #n ")" ::: "memory")

__device__ __forceinline__ u16 f2bf(float f) {
  union { float ff; uint32_t u; } a; a.ff = f;
  return (u16)((a.u + 0x7fffu + ((a.u >> 16) & 1u)) >> 16);  // RNE
}

__device__ __forceinline__ uint32_t cvtpk(float lo, float hi) {
  uint32_t r;
  asm("v_cvt_pk_bf16_f32 %0, %1, %2" : "=v"(r) : "v"(lo), "v"(hi));
  return r;
}

// ---------------- fused fp32 -> bf16 convert ----------------
__global__ void cvt_all(const float* __restrict__ x,  const float* __restrict__ wq,
                        const float* __restrict__ wk, const float* __restrict__ wv,
                        const float* __restrict__ wo,
                        u16* __restrict__ xb,  u16* __restrict__ wqb,
                        u16* __restrict__ wkb, u16* __restrict__ wvb,
                        u16* __restrict__ wob) {
  const int total = 6291456;
  int i = blockIdx.x * blockDim.x + threadIdx.x;
  const int stride = gridDim.x * blockDim.x;
  for (; i < total; i += stride) {
    const int r = i >> 20;
    const float* src; u16* dst; int off;
    if (r < 2)       { src = x;  dst = xb;  off = i; }
    else if (r == 2) { src = wq; dst = wqb; off = i - (2 << 20); }
    else if (r == 3) { src = wk; dst = wkb; off = i - (3 << 20); }
    else if (r == 4) { src = wv; dst = wvb; off = i - (4 << 20); }
    else             { src = wo; dst = wob; off = i - (5 << 20); }
    float4 v = reinterpret_cast<const float4*>(src)[off];
    uint2 pk;
    pk.x = (uint32_t)f2bf(v.x) | ((uint32_t)f2bf(v.y) << 16);
    pk.y = (uint32_t)f2bf(v.z) | ((uint32_t)f2bf(v.w) << 16);
    reinterpret_cast<uint2*>(dst)[off] = pk;
  }
}

// ---------------- rope tables ----------------
__global__ void rope_kernel(float* __restrict__ rc, float* __restrict__ rs) {
  const int i = blockIdx.x * blockDim.x + threadIdx.x;
  const int s = i >> 6, f = i & 63;
  const double inv = exp(-(double)f * (log(10000.0) / 64.0));
  const double a = (double)s * inv;
  rc[i] = (float)cos(a);
  rs[i] = (float)sin(a);
}

// ---------------- QKV GEMM: 256x256 tile, BK=64, m201 8-phase schedule ----------------
// grid 384 = 16 mt x 24 ct (ct: 3 regions x 8). 8 waves (2M x 4N), per-wave 128x64.
// LDS: 2 buffers x (A 32KB + B 32KB), fragment-order: unit v=((kc*16+MF)*4+lk)*16+lr.
// Per K-tile 4 phases; each phase issues one half-tile (2 global_load_lds) for a
// 2-tile-deep pipeline; counted vmcnt(8) at odd-phase ends only (ledger in comments).
__global__ __launch_bounds__(512, 2)
void gemm_qkv256(const u16* __restrict__ A,
                 const u16* __restrict__ B0w, const u16* __restrict__ B1w,
                 const u16* __restrict__ B2w,
                 u16* __restrict__ qout, u16* __restrict__ kout, u16* __restrict__ vtout,
                 const float* __restrict__ rc, const float* __restrict__ rs) {
  constexpr int K = DMODEL;
  constexpr int NT = K / 64;            // 32 K-tiles
  __shared__ __align__(16) u16 sm[2][2][16384];   // [buf][A/B][32KB tile]

  const int g = (blockIdx.x & 7) * 48 + (blockIdx.x >> 3);   // XCD-contiguous
  const int mt = g / 24, ct = g % 24;
  const int region = ct >> 3;
  const u16* Bw = region == 0 ? B0w : region == 1 ? B1w : B2w;
  const int brow = mt * 256;
  const int bcoll = (ct & 7) * 256;

  const int tid = threadIdx.x;
  const int w = tid >> 6, lane = tid & 63;
  const int lr = lane & 15, lk = lane >> 4;
  const int wm = w >> 2, wn = w & 3;

  const u16* Ag = A  + (size_t)brow * K;
  const u16* Bg = Bw + (size_t)bcoll * K;

  f32x4 acc[8][4] = {};

  // stage half h (=kc region) of tile tt for matrix mat into buf tt&1
  auto stage = [&](int mat, int tt, int h) {
#pragma unroll
    for (int i = 0; i < 2; ++i) {
      const int u = h * 1024 + i * 512 + tid;     // = kc*1024 + MF*64 + lk*16 + lr
      const int MF = (u >> 6) & 15, lkk = (u >> 4) & 3, lrr = u & 15;
      const u16* src = (mat == 0 ? Ag : Bg) + (size_t)(MF * 16 + lrr) * K + tt * 64 + h * 32 + lkk * 8;
      __builtin_amdgcn_global_load_lds((const AS1 void*)src,
          (AS3 void*)(&sm[tt & 1][mat][(size_t)(h * 1024 + i * 512 + w * 64) * 8]), 16, 0, 0);
    }
  };

  // prologue: A0(0),B0(0),A1(0),B1(0),A0(1),B0(1); wait A0(0),B0(0) resident
  stage(0, 0, 0); stage(1, 0, 0);
  stage(0, 0, 1); stage(1, 0, 1);
  stage(0, 1, 0); stage(1, 1, 0);
  WAITVM(8);
  BAR();

  for (int t = 0; t < NT; ++t) {
    const u16* Asl = &sm[t & 1][0][0];
    const u16* Bsl = &sm[t & 1][1][0];
    bf16x8 a[4], b[4];
    // ---- phase j0: kc0, mh0 ----
#pragma unroll
    for (int ml = 0; ml < 4; ++ml)
      a[ml] = *reinterpret_cast<const bf16x8*>(Asl + (((wm * 8 + ml) * 4 + lk) * 16 + lr) * 8);
#pragma unroll
    for (int nf = 0; nf < 4; ++nf)
      b[nf] = *reinterpret_cast<const bf16x8*>(Bsl + (((wn * 4 + nf) * 4 + lk) * 16 + lr) * 8);
    if (t + 1 < NT) stage(0, t + 1, 1);          // A1(t+1) -> other buffer
    BAR();
    __builtin_amdgcn_s_setprio(1);
#pragma unroll
    for (int ml = 0; ml < 4; ++ml)
#pragma unroll
      for (int nf = 0; nf < 4; ++nf)
        acc[ml][nf] = __builtin_amdgcn_mfma_f32_16x16x32_bf16(a[ml], b[nf], acc[ml][nf], 0, 0, 0);
    __builtin_amdgcn_s_setprio(0);
    BAR();
    // ---- phase j1: kc0, mh1 ----
    bf16x8 a2[4];
#pragma unroll
    for (int ml = 0; ml < 4; ++ml)
      a2[ml] = *reinterpret_cast<const bf16x8*>(Asl + (((wm * 8 + 4 + ml) * 4 + lk) * 16 + lr) * 8);
    if (t + 1 < NT) stage(1, t + 1, 1);          // B1(t+1)
    BAR();
    __builtin_amdgcn_s_setprio(1);
#pragma unroll
    for (int ml = 0; ml < 4; ++ml)
#pragma unroll
      for (int nf = 0; nf < 4; ++nf)
        acc[4 + ml][nf] = __builtin_amdgcn_mfma_f32_16x16x32_bf16(a2[ml], b[nf], acc[4 + ml][nf], 0, 0, 0);
    __builtin_amdgcn_s_setprio(0);
    // ledger: outstanding = {A0(t+1),B0(t+1),A1(t+1),B1(t+1)} = 8 -> retires kc1(t)
    if (t + 1 < NT) { WAITVM(8); } else { WAITVM(0); }
    BAR();
    // ---- phase j2: kc1, mh0 ----
#pragma unroll
    for (int ml = 0; ml < 4; ++ml)
      a[ml] = *reinterpret_cast<const bf16x8*>(Asl + ((((16 + wm * 8 + ml) * 4) + lk) * 16 + lr) * 8);
#pragma unroll
    for (int nf = 0; nf < 4; ++nf)
      b[nf] = *reinterpret_cast<const bf16x8*>(Bsl + ((((16 + wn * 4 + nf) * 4) + lk) * 16 + lr) * 8);
    if (t + 2 < NT) stage(0, t + 2, 0);          // A0(t+2) -> this buffer, kc0 (done reading)
    BAR();
    __builtin_amdgcn_s_setprio(1);
#pragma unroll
    for (int ml = 0; ml < 4; ++ml)
#pragma unroll
      for (int nf = 0; nf < 4; ++nf)
        acc[ml][nf] = __builtin_amdgcn_mfma_f32_16x16x32_bf16(a[ml], b[nf], acc[ml][nf], 0, 0, 0);
    __builtin_amdgcn_s_setprio(0);
    BAR();
    // ---- phase j3: kc1, mh1 ----
#pragma unroll
    for (int ml = 0; ml < 4; ++ml)
      a2[ml] = *reinterpret_cast<const bf16x8*>(Asl + ((((16 + wm * 8 + 4 + ml) * 4) + lk) * 16 + lr) * 8);
    if (t + 2 < NT) stage(1, t + 2, 0);          // B0(t+2)
    BAR();
    __builtin_amdgcn_s_setprio(1);
#pragma unroll
    for (int ml = 0; ml < 4; ++ml)
#pragma unroll
      for (int nf = 0; nf < 4; ++nf)
        acc[4 + ml][nf] = __builtin_amdgcn_mfma_f32_16x16x32_bf16(a2[ml], b[nf], acc[4 + ml][nf], 0, 0, 0);
    __builtin_amdgcn_s_setprio(0);
    // ledger: outstanding = {A1(t+1),B1(t+1),A0(t+2),B0(t+2)} = 8 -> retires kc0(t+1)
    if (t + 2 < NT) { WAITVM(8); } else if (t + 2 == NT) { WAITVM(4); }
    BAR();
  }

  // ---- epilogue ----  C frag: col = lane&15, row = lk*4 + j (m89)
  if (region == 2) {            // V: transposed [B,H,Dh,S] bf16
#pragma unroll
    for (int mf = 0; mf < 8; ++mf) {
      const int gm0 = brow + wm * 128 + mf * 16 + lk * 4;
      const int b_ = gm0 >> 11, s0 = gm0 & 2047;
#pragma unroll
      for (int nf = 0; nf < 4; ++nf) {
        const int gn = bcoll + wn * 64 + nf * 16 + lr;
        const int h = gn >> 7, dh = gn & 127;
        uint2 pk;
        pk.x = (uint32_t)f2bf(acc[mf][nf][0]) | ((uint32_t)f2bf(acc[mf][nf][1]) << 16);
        pk.y = (uint32_t)f2bf(acc[mf][nf][2]) | ((uint32_t)f2bf(acc[mf][nf][3]) << 16);
        *reinterpret_cast<uint2*>(&vtout[((size_t)((b_ * NHEAD + h) * HDIM + dh)) * S_LEN + s0]) = pk;
      }
    }
  } else {                      // Q/K: rope (+scale for Q)
    u16* QK = region == 0 ? qout : kout;
#pragma unroll
    for (int mf = 0; mf < 8; ++mf) {
      const int gm0 = brow + wm * 128 + mf * 16 + lk * 4;
      const int b_ = gm0 >> 11, s0 = gm0 & 2047;
#pragma unroll
      for (int nf = 0; nf < 4; ++nf) {
        const int gn = bcoll + wn * 64 + nf * 16 + lr;
        const int h = gn >> 7, dh = gn & 127;
        const int fi = dh >> 1;
        const bool ev = (dh & 1) == 0;
#pragma unroll
        for (int j = 0; j < 4; ++j) {
          float v = acc[mf][nf][j];
          float pp = __shfl_xor(v, 1, 64);
          const float c  = rc[(s0 + j) * 64 + fi];
          const float sn = rs[(s0 + j) * 64 + fi];
          float oo = ev ? (v * c - pp * sn) : (pp * sn + v * c);
          if (region == 0) oo *= 0.08838834764831845f;
          QK[((size_t)(b_ * NHEAD + h) * S_LEN + (s0 + j)) * HDIM + dh] = f2bf(oo);
        }
      }
    }
  }
}

// ---------------- O projection: proven 128x128 m97-structure ----------------
__global__ __launch_bounds__(256, 2)
void gemm_o(const u16* __restrict__ A, const u16* __restrict__ Bw,
            float* __restrict__ O) {
  constexpr int K = DMODEL;
  constexpr int BK = 64;
  __shared__ __align__(16) u16 As[128 * BK];
  __shared__ __align__(16) u16 Bs[128 * BK];
  const int tid = threadIdx.x;
  const int w = tid >> 6, lane = tid & 63;
  const int lr = lane & 15, lk = lane >> 4;
  const int wm = w >> 1, wn = w & 1;
  const int brow = blockIdx.y * 128;
  const int bcol = blockIdx.x * 128;

  f32x4 acc[4][4] = {};

  const int st_row = w * 32 + (lane >> 3);
  const int st_col = (lane & 7) * 8;
  const u16* Ag = A  + (size_t)(brow + st_row) * K + st_col;
  const u16* Bg = Bw + (size_t)(bcol + st_row) * K + st_col;
  u16* AsW = As + w * 32 * BK;
  u16* BsW = Bs + w * 32 * BK;

  for (int k0 = 0; k0 < K; k0 += BK) {
#pragma unroll
    for (int i = 0; i < 4; ++i)
      __builtin_amdgcn_global_load_lds(
          (const AS1 void*)(Ag + (size_t)i * 8 * K + k0),
          (AS3 void*)(AsW + i * 8 * BK), 16, 0, 0);
#pragma unroll
    for (int i = 0; i < 4; ++i)
      __builtin_amdgcn_global_load_lds(
          (const AS1 void*)(Bg + (size_t)i * 8 * K + k0),
          (AS3 void*)(BsW + i * 8 * BK), 16, 0, 0);
    __syncthreads();
#pragma unroll
    for (int kc = 0; kc < 2; ++kc) {
      bf16x8 a[4], b[4];
#pragma unroll
      for (int m = 0; m < 4; ++m)
        a[m] = *reinterpret_cast<const bf16x8*>(&As[(wm * 64 + m * 16 + lr) * BK + kc * 32 + lk * 8]);
#pragma unroll
      for (int n = 0; n < 4; ++n)
        b[n] = *reinterpret_cast<const bf16x8*>(&Bs[(wn * 64 + n * 16 + lr) * BK + kc * 32 + lk * 8]);
#pragma unroll
      for (int m = 0; m < 4; ++m)
#pragma unroll
        for (int n = 0; n < 4; ++n)
          acc[m][n] = __builtin_amdgcn_mfma_f32_16x16x32_bf16(a[m], b[n], acc[m][n], 0, 0, 0);
    }
    __syncthreads();
  }

#pragma unroll
  for (int m = 0; m < 4; ++m) {
    const int gm0 = brow + wm * 64 + m * 16 + lk * 4;
#pragma unroll
    for (int n = 0; n < 4; ++n) {
      const int gn = bcol + wn * 64 + n * 16 + lr;
#pragma unroll
      for (int j = 0; j < 4; ++j)
        O[(size_t)(gm0 + j) * DMODEL + gn] = acc[m][n][j];
    }
  }
}

// ---------------- sliding-window flash attention, LDS-staged K/V ----------------
__global__ __launch_bounds__(256, 2)
void swa3_kernel(const u16* __restrict__ Qp, const u16* __restrict__ Kp,
                 const u16* __restrict__ Vt, u16* __restrict__ AO) {
  __shared__ __align__(16) u16 Ksh[2][64 * 128];
  __shared__ __align__(16) u16 Vsh[2][128 * 64];

  const int lin = blockIdx.x + gridDim.x * blockIdx.y;
  const int slot = lin >> 3;
  const int bh = (lin & 7) * 4 + (slot >> 4);
  const int qt = slot & 15;

  const int w = threadIdx.x >> 6;
  const int lane = threadIdx.x & 63;
  const int lq = lane & 31, hi = lane >> 5;
  const int qb_blk = qt * 128;
  const int qw = qb_blk + w * 32;
  const int qq = qw + lq;

  const u16* Qb = Qp + (size_t)bh * S_LEN * HDIM;
  const u16* Kb = Kp + (size_t)bh * S_LEN * HDIM;
  const u16* Vb = Vt + (size_t)bh * HDIM * S_LEN;

  bf16x8 qf[8];
#pragma unroll
  for (int s = 0; s < 8; ++s)
    qf[s] = *reinterpret_cast<const bf16x8*>(&Qb[(size_t)qq * HDIM + s * 16 + hi * 8]);

  f32x16 ot[4] = {};
  float m = 0.f, lsum = 0.f;

  const int c_lo = (qb_blk >= WIN) ? qb_blk - WIN : 0;
  const int c_hi = qb_blk + 128;

  auto stage = [&](int buf, int kc) {
#pragma unroll
    for (int i = 0; i < 4; ++i) {
      const int u = i * 256 + w * 64 + lane;
      const int row = u >> 4, sl = (u & 15) ^ (row & 7);
      __builtin_amdgcn_global_load_lds(
          (const AS1 void*)(Kb + (size_t)(kc + row) * HDIM + sl * 8),
          (AS3 void*)(&Ksh[buf][(size_t)(i * 256 + w * 64) * 8]), 16, 0, 0);
    }
#pragma unroll
    for (int i = 0; i < 4; ++i) {
      const int u = i * 256 + w * 64 + lane;
      const int row = u >> 3, sl = (u & 7) ^ (row & 7);
      __builtin_amdgcn_global_load_lds(
          (const AS1 void*)(Vb + (size_t)row * S_LEN + kc + sl * 8),
          (AS3 void*)(&Vsh[buf][(size_t)(i * 256 + w * 64) * 8]), 16, 0, 0);
    }
  };

  int buf = 0;
  stage(0, c_lo);
  __syncthreads();

  for (int kc = c_lo; kc < c_hi; kc += 64, buf ^= 1) {
    if (kc + 64 < c_hi) stage(buf ^ 1, kc + 64);

#pragma unroll
    for (int half = 0; half < 2; ++half) {
      const int kch = kc + half * 32;
      if (kch > qw + 31 || kch < qw - 542) continue;

      f32x16 P = {};
#pragma unroll
      for (int s = 0; s < 8; ++s) {
        const int row = half * 32 + lq;
        const int byte = row * 256 + ((s * 32 + hi * 16) ^ ((row & 7) << 4));
        bf16x8 kf = *reinterpret_cast<const bf16x8*>(&Ksh[buf][byte >> 1]);
        P = __builtin_amdgcn_mfma_f32_32x32x16_bf16(kf, qf[s], P, 0, 0, 0);
      }

      const bool needmask = (kch + 32 > qw) || (qw + 31 - kch >= WIN);
      float p[16];
      float pmax = -1e30f;
#pragma unroll
      for (int r = 0; r < 16; ++r) {
        float v = P[r];
        if (needmask) {
          const int kk = kch + (r & 3) + ((r >> 2) << 3) + hi * 4;
          const bool keep = (qq >= kk) && (qq - kk < WIN);
          v = keep ? v : -1e30f;
        }
        p[r] = v;
        pmax = fmaxf(pmax, v);
      }

      if (__any(pmax - m > 8.f)) {
        const float rm = fmaxf(pmax, __shfl_xor(pmax, 32, 64));
        const float mnew = fmaxf(m, rm);
        const float alpha = __expf(m - mnew);
        lsum *= alpha;
#pragma unroll
        for (int dt = 0; dt < 4; ++dt)
#pragma unroll
          for (int r = 0; r < 16; ++r) ot[dt][r] *= alpha;
        m = mnew;
      }

      float ls = 0.f;
#pragma unroll
      for (int r = 0; r < 16; ++r) {
        p[r] = __expf(p[r] - m);
        ls += p[r];
      }
      lsum += ls;

      uint32_t W[8];
#pragma unroll
      for (int i = 0; i < 8; ++i) W[i] = cvtpk(p[2 * i], p[2 * i + 1]);
      u32x2v r02 = __builtin_amdgcn_permlane32_swap(W[0], W[2], false, false);
      u32x2v r13 = __builtin_amdgcn_permlane32_swap(W[1], W[3], false, false);
      u32x2v r46 = __builtin_amdgcn_permlane32_swap(W[4], W[6], false, false);
      u32x2v r57 = __builtin_amdgcn_permlane32_swap(W[5], W[7], false, false);

#pragma unroll
      for (int ks = 0; ks < 2; ++ks) {
        union { uint32_t u[4]; bf16x8 v; } pb;
        if (ks == 0) { pb.u[0] = r02[0]; pb.u[1] = r13[0]; pb.u[2] = r02[1]; pb.u[3] = r13[1]; }
        else         { pb.u[0] = r46[0]; pb.u[1] = r57[0]; pb.u[2] = r46[1]; pb.u[3] = r57[1]; }
#pragma unroll
        for (int dt = 0; dt < 4; ++dt) {
          const int d = dt * 32 + lq;
          const int byte = d * 128 + ((half * 64 + ks * 32 + hi * 16) ^ ((d & 7) << 4));
          bf16x8 vf = *reinterpret_cast<const bf16x8*>(&Vsh[buf][byte >> 1]);
          ot[dt] = __builtin_amdgcn_mfma_f32_32x32x16_bf16(vf, pb.v, ot[dt], 0, 0, 0);
        }
      }
    }
    __syncthreads();
  }

  const float lf = lsum + __shfl_xor(lsum, 32, 64);
  const float inv = 1.f / lf;
  const int b = bh >> 4, h = bh & 15;
  u16* Ob = AO + (size_t)(b * S_LEN + qq) * DMODEL + h * HDIM;
#pragma unroll
  for (int dt = 0; dt < 4; ++dt)
#pragma unroll
    for (int rq = 0; rq < 4; ++rq) {
      uint2 pk;
      pk.x = cvtpk(ot[dt][rq * 4 + 0] * inv, ot[dt][rq * 4 + 1] * inv);
      pk.y = cvtpk(ot[dt][rq * 4 + 2] * inv, ot[dt][rq * 4 + 3] * inv);
      *reinterpret_cast<uint2*>(&Ob[dt * 32 + rq * 8 + hi * 4]) = pk;
    }
}

extern "C" void kernel_launch(void* const* d_in, const int* in_sizes, int n_in,
                              void* d_out, int out_size, void* d_ws, size_t ws_size,
                              hipStream_t stream) {
  const float* x  = (const float*)d_in[0];
  const float* Wq = (const float*)d_in[1];
  const float* Wk = (const float*)d_in[2];
  const float* Wv = (const float*)d_in[3];
  const float* Wo = (const float*)d_in[4];
  float* out = (float*)d_out;

  u16* p = (u16*)d_ws;
  u16* xb  = p; p += (size_t)4096 * 2048;
  u16* wqb = p; p += (size_t)2048 * 2048;
  u16* wkb = p; p += (size_t)2048 * 2048;
  u16* wvb = p; p += (size_t)2048 * 2048;
  u16* wob = p; p += (size_t)2048 * 2048;
  u16* qb  = p; p += (size_t)32 * 2048 * 128;
  u16* kb  = p; p += (size_t)32 * 2048 * 128;
  u16* vtb = p; p += (size_t)32 * 128 * 2048;
  u16* aob = p; p += (size_t)4096 * 2048;
  float* rc = (float*)p;
  float* rs = rc + (size_t)2048 * 64;

  cvt_all<<<3072, 256, 0, stream>>>(x, Wq, Wk, Wv, Wo, xb, wqb, wkb, wvb, wob);
  rope_kernel<<<512, 256, 0, stream>>>(rc, rs);
  gemm_qkv256<<<384, 512, 0, stream>>>(xb, wqb, wkb, wvb, qb, kb, vtb, rc, rs);
  swa3_kernel<<<dim3(16, 32), 256, 0, stream>>>(qb, kb, vtb, aob);
  gemm_o<<<dim3(16, 32), 256, 0, stream>>>(aob, wob, out);
}